// Round 11
// baseline (198.539 us; speedup 1.0000x reference)
//
#include <hip/hip_runtime.h>
#include <hip/hip_bf16.h>

// ConvSelfAttentionModule: B=4, C=256, CQK=128, N=4096 (64x64), fp32 in/out.
// R19 = R8 (proven 178.4us best) + AV re-tile in k_fav ONLY.
// R10 lesson: barrier COUNT is not the cost (2-tile super-iters were
// neutral). Cycle model: per iter per CU, MFMA ~930 cyc but LDS ~64KB reads
// (every wave reads the whole 8KB sE) + 16KB writes ~ 900-1000 cyc -> LDS
// pipe co-bottleneck, serialized against MFMA by the QK->write->bar->read->AV
// chain. Fix: AV tiling 32c x 64j -> 64c x 32j per wave: each wave reads only
// its j-half of sE (4KB) -> LDS reads halve. QK phase, sE writes, swizzle,
// barrier structure byte-identical to the thrice-proven R4 body; only V-frag
// base, e-read row offset, acc extents, epilogue mapping change (all
// deterministic). launch_bounds(512,1): vf regs double (~170 VGPR), grid is
// 1 wg/CU anyway; avoids R3-style cap-spill.
//   k_wcvt   : W -> f16 fragment-tiled [R16]
//   k_xsplit : x -> fragment-tiled f16 [R16]
//   k_proj   : register-direct projections, no LDS/barriers [R16]
//   k_rows   : QK^T + exp + partial row sums (widened, 128 j/wg) [R15/R8]
//   k_rsum   : rinv[b][i] = 1 / sum_j exp(S[i,j]) [R15]
//   k_fav    : fused recompute+AV, AV re-tiled (above)

typedef _Float16 f16;
typedef _Float16 f16x4v __attribute__((ext_vector_type(4)));
typedef _Float16 f16x8v __attribute__((ext_vector_type(8)));
typedef float f32x4v __attribute__((ext_vector_type(4)));

static __device__ __forceinline__ f32x4v mfma16(f16x8v a, f16x8v b, f32x4v c) {
  // A-frag m=lane&15,k=quad*8+e; B-frag n=lane&15,k=quad*8+e
  // D: col(n)=lane&15, row(m)=quad*4+reg
  return __builtin_amdgcn_mfma_f32_16x16x32_f16(a, b, c, 0, 0, 0);
}

// ---------------- kernel 0a: weight convert -> fragment-tiled ----------------
// wT elem (o,c): (o>>4)*4096 + (c>>5)*512 + ((c>>3)&3)*128 + (o&15)*8 + (c&7)
__global__ void k_wcvt(const float* __restrict__ wq, const float* __restrict__ bq,
                       const float* __restrict__ wk, const float* __restrict__ bk,
                       const float* __restrict__ wv, const float* __restrict__ bv,
                       f16* __restrict__ wh, float* __restrict__ bcat) {
  int o = blockIdx.x;          // 512 rows: 0-127 q, 128-255 k, 256-511 v
  int c = threadIdx.x;         // 256
  const float* wrow; float bias;
  if (o < 128)      { wrow = wq + (size_t)o * 256;         bias = bq[o]; }
  else if (o < 256) { wrow = wk + (size_t)(o - 128) * 256; bias = bk[o - 128]; }
  else              { wrow = wv + (size_t)(o - 256) * 256; bias = bv[o - 256]; }
  wh[(size_t)(o >> 4) * 4096 + (size_t)(c >> 5) * 512 +
     (size_t)((c >> 3) & 3) * 128 + (o & 15) * 8 + (c & 7)] = (f16)wrow[c];
  if (c == 0) bcat[o] = bias;
}

// ---------------- kernel 0b: x transpose -> fragment-tiled f16 ----------------
// xTf elem (t,c): b*1048576 + (t>>4)*4096 + (c>>5)*512 + ((c>>3)&3)*128
//                 + (t&15)*8 + (c&7)
__global__ void k_xsplit(const float* __restrict__ x, f16* __restrict__ xh) {
  __shared__ float t[64][65];
  int b = blockIdx.z, c0 = blockIdx.y * 64, n0 = blockIdx.x * 64;
  int tx = threadIdx.x & 63, ty = threadIdx.x >> 6;
  const float* xb = x + ((size_t)b * 256 + c0) * 4096 + n0;
#pragma unroll
  for (int r = ty; r < 64; r += 4) t[r][tx] = xb[(size_t)r * 4096 + tx];
  __syncthreads();
  f16* xbb = xh + (size_t)b * 1048576;
#pragma unroll
  for (int k2 = 0; k2 < 2; k2++) {
    int id = k2 * 256 + threadIdx.x;
    int tok = id & 63, oct = id >> 6;          // oct = 8-channel group 0..7
    int tt = n0 + tok;
    f16x8v v;
#pragma unroll
    for (int e = 0; e < 8; e++) v[e] = (f16)t[oct * 8 + e][tok];
    size_t addr = (size_t)(tt >> 4) * 4096 +
                  (size_t)((c0 >> 5) + (oct >> 2)) * 512 +
                  (size_t)(oct & 3) * 128 + (tt & 15) * 8;
    *(f16x8v*)&xbb[addr] = v;
  }
}

// ---------------- kernel 1: projections, register-direct [R16] ----------------
__global__ void __launch_bounds__(512, 1)
k_proj(const f16* __restrict__ xh, const f16* __restrict__ wh,
       const float* __restrict__ bcat, f16* __restrict__ qT,
       f16* __restrict__ kT, f16* __restrict__ vT) {
  int ob = blockIdx.x, th = blockIdx.y, b = blockIdx.z;
  int tid = threadIdx.x, l = tid & 63, w = tid >> 6;
  int col = l & 15, quad = l >> 4;
  int tt = w & 3, oh = w >> 2;
  int OT0 = ob * 4 + oh * 2;                   // first of 2 resident o-tiles
  const f16* wtb = wh + (size_t)OT0 * 4096 + l * 8;
  f16x8v wb[2][8];
#pragma unroll
  for (int jt = 0; jt < 2; jt++)
#pragma unroll
    for (int ks = 0; ks < 8; ks++)
      wb[jt][ks] = *(const f16x8v*)(wtb + jt * 4096 + ks * 512);
  float bias0 = bcat[OT0 * 16 + col];
  float bias1 = bcat[OT0 * 16 + 16 + col];
  const f16* atb = xh + (size_t)b * 1048576 + (size_t)(th * 32 + tt) * 4096 + l * 8;
  f16x8v afA[8], afB[8];
#pragma unroll
  for (int ks = 0; ks < 8; ks++) afA[ks] = *(const f16x8v*)(atb + ks * 512);

#define PROJ_BODY(IT, AF, AN, PREF)                                            \
  {                                                                            \
    if (PREF) {                                                                \
      _Pragma("unroll") for (int ks = 0; ks < 8; ks++)                         \
        AN[ks] = *(const f16x8v*)(atb + (size_t)((IT) + 1) * 16384 + ks * 512);\
    }                                                                          \
    f32x4v s0 = {}, s1 = {};                                                   \
    _Pragma("unroll") for (int ks = 0; ks < 8; ks++) {                         \
      s0 = mfma16(AF[ks], wb[0][ks], s0);                                      \
      s1 = mfma16(AF[ks], wb[1][ks], s1);                                      \
    }                                                                          \
    int T = th * 32 + (IT) * 4 + tt;                                           \
    if (ob < 4) {                                                              \
      f16* dst = (ob < 2) ? qT : kT;                                           \
      _Pragma("unroll") for (int jt = 0; jt < 2; jt++) {                       \
        int o = OT0 * 16 + jt * 16 + col;                                      \
        int d = o & 127;                                                       \
        float bs = jt ? bias1 : bias0;                                         \
        size_t base = (size_t)b * 524288 + (size_t)T * 2048 +                  \
                      (size_t)(d >> 5) * 512 + (size_t)((d >> 3) & 3) * 128 +  \
                      (d & 7);                                                 \
        float sv0 = jt ? s1[0] : s0[0], sv1 = jt ? s1[1] : s0[1];              \
        float sv2 = jt ? s1[2] : s0[2], sv3 = jt ? s1[3] : s0[3];              \
        dst[base + (quad * 4 + 0) * 8] = (f16)(sv0 + bs);                      \
        dst[base + (quad * 4 + 1) * 8] = (f16)(sv1 + bs);                      \
        dst[base + (quad * 4 + 2) * 8] = (f16)(sv2 + bs);                      \
        dst[base + (quad * 4 + 3) * 8] = (f16)(sv3 + bs);                      \
      }                                                                        \
    } else {                                                                   \
      int i0 = T * 16 + quad * 4;                                              \
      size_t ibase = (size_t)b * 1048576 + (size_t)(i0 >> 5) * 512 +           \
                     (size_t)((i0 >> 3) & 3) * 128 + (i0 & 7);                 \
      _Pragma("unroll") for (int jt = 0; jt < 2; jt++) {                       \
        int c = OT0 * 16 + jt * 16 + col - 256;                                \
        float bs = jt ? bias1 : bias0;                                         \
        f16x4v pv;                                                             \
        _Pragma("unroll") for (int rg = 0; rg < 4; rg++)                       \
          pv[rg] = (f16)((jt ? s1[rg] : s0[rg]) + bs);                         \
        *(f16x4v*)&vT[ibase + (size_t)(c >> 4) * 65536 + (c & 15) * 8] = pv;   \
      }                                                                        \
    }                                                                          \
  }

  for (int itp = 0; itp < 4; itp++) {
    int itA = itp * 2;
    PROJ_BODY(itA, afA, afB, true)
    PROJ_BODY(itA + 1, afB, afA, itp < 3)
  }
#undef PROJ_BODY
}

// ---------------- kernel 2: row sums of exp(S), widened (128 j per wg) [R8] ----------------
__global__ void __launch_bounds__(512, 2)
k_rows(const f16* __restrict__ qT, const f16* __restrict__ kT,
       float* __restrict__ partial) {
  int jblk = blockIdx.x, ih = blockIdx.y, b = blockIdx.z;
  int tid = threadIdx.x, l = tid & 63, w = tid >> 6;
  int col = l & 15;
  int ti = w & 3, jh = w >> 2;
  const f16* ktb = kT + (size_t)b * 524288 + (size_t)(jblk * 8 + jh * 4) * 2048 + l * 8;
  const f16* qtb = qT + (size_t)b * 524288 + (size_t)ti * 2048 + l * 8;
  f16x8v ka[4][4];
#pragma unroll
  for (int jt = 0; jt < 4; jt++)
#pragma unroll
    for (int ks = 0; ks < 4; ks++)
      ka[jt][ks] = *(const f16x8v*)(ktb + jt * 2048 + ks * 512);
  float* pout = partial + ((size_t)(b * 32 + jblk) * 2 + jh) * 4096 + ti * 16 + col;
  int it0 = ih * 32;
  f16x8v qfA[4], qfB[4];
#pragma unroll
  for (int ks = 0; ks < 4; ks++)
    qfA[ks] = *(const f16x8v*)(qtb + (size_t)it0 * 8192 + ks * 512);

#define ROWS_BODY(IT, QF, QN, PREF)                                           \
  {                                                                           \
    if (PREF) {                                                               \
      _Pragma("unroll") for (int ks = 0; ks < 4; ks++)                        \
        QN[ks] = *(const f16x8v*)(qtb + (size_t)((IT) + 1) * 8192 + ks * 512);\
    }                                                                         \
    f32x4v s[4] = {};                                                         \
    _Pragma("unroll") for (int ks = 0; ks < 4; ks++) {                        \
      s[0] = mfma16(ka[0][ks], QF[ks], s[0]);                                 \
      s[1] = mfma16(ka[1][ks], QF[ks], s[1]);                                 \
      s[2] = mfma16(ka[2][ks], QF[ks], s[2]);                                 \
      s[3] = mfma16(ka[3][ks], QF[ks], s[3]);                                 \
    }                                                                         \
    float t = 0.f;                                                            \
    _Pragma("unroll") for (int jt = 0; jt < 4; jt++)                          \
      _Pragma("unroll") for (int rg = 0; rg < 4; rg++)                        \
        t += __expf(s[jt][rg]);                                               \
    t += __shfl_xor(t, 16);                                                   \
    t += __shfl_xor(t, 32);                                                   \
    if (l < 16) pout[(size_t)(IT) * 64] = t;                                  \
  }

  for (int itp = 0; itp < 16; itp++) {
    int itA = it0 + itp * 2;
    ROWS_BODY(itA, qfA, qfB, true)
    ROWS_BODY(itA + 1, qfB, qfA, itp < 15)
  }
#undef ROWS_BODY
}

// ---------------- kernel 3: combine partials -> rinv = 1/rowsum ----------------
__global__ void k_rsum(const float* __restrict__ partial, float* __restrict__ rinv) {
  int b = blockIdx.y;
  int i = blockIdx.x * 256 + threadIdx.x;
  const float* p = partial + (size_t)b * 64 * 4096 + i;
  float s = 0.f;
#pragma unroll 8
  for (int jb = 0; jb < 64; jb++) s += p[(size_t)jb * 4096];
  rinv[(size_t)b * 4096 + i] = 1.0f / s;
}

// ---------------- kernel 4: fused recompute + AV, AV re-tiled 64c x 32j ----------------
// Per wg: batch b, j-cols [j0,j0+64), all 256 c. Loop i in 64-steps:
//   QK (wave ti=w&3, tjb=(w>>2)*2): S^T = mfma(K_regs, Q_regs)   [R4 exact]
//   E' = exp(S)*rinv -> sE (dbuf, XOR-swizzled, b16 scatter)     [R4 exact]
//   lgkm-only barrier                                            [R4 exact]
//   AV (wave cg=w&3, jh=w>>2): acc[4][2] += mfma(V[cg*4+mt], E'[jh-half])
//     -> each wave reads only 4KB of sE (was 8KB): LDS reads halved.
__global__ void __launch_bounds__(512, 1)
k_fav(const f16* __restrict__ qT, const f16* __restrict__ kT,
      const f16* __restrict__ vT, const float* __restrict__ rinv,
      const float* __restrict__ x, const float* __restrict__ gamma,
      float* __restrict__ out) {
  __shared__ f16 sE[2][4096];   // [buf][64 j][64 i], 8-elem i-groups XOR(j&7)
  // XCD-chunked swizzle: 256 wgs, 8 XCDs -> contiguous 32-wg slice per XCD.
  int wg = blockIdx.x;
  int lg = (wg & 7) * 32 + (wg >> 3);
  int b = lg >> 6, j0 = (lg & 63) * 64;
  int tid = threadIdx.x, l = tid & 63, w = tid >> 6;
  int col = l & 15, quad = l >> 4;
  int ti = w & 3, tjb = (w >> 2) * 2;   // QK roles (unchanged)
  int cg = w & 3, jh = w >> 2;          // AV roles: c-group, j-half
  const f16* ktb = kT + (size_t)b * 524288 + (size_t)(j0 / 16 + tjb) * 2048 + l * 8;
  const f16* qtb = qT + (size_t)b * 524288 + (size_t)ti * 2048 + l * 8;
  const f16* vtb = vT + (size_t)b * 1048576 + (size_t)(cg * 4) * 65536 + l * 8;
  const float* rp = rinv + (size_t)b * 4096 + ti * 16 + col;
  // K fragments: resident whole kernel
  f16x8v ka0[4], ka1[4];
#pragma unroll
  for (int ks = 0; ks < 4; ks++) {
    ka0[ks] = *(const f16x8v*)(ktb + ks * 512);
    ka1[ks] = *(const f16x8v*)(ktb + 2048 + ks * 512);
  }
  f16x8v qfA[4], qfB[4], vfA[4][2], vfB[4][2];
  float rvA, rvB;
#pragma unroll
  for (int ks = 0; ks < 4; ks++) qfA[ks] = *(const f16x8v*)(qtb + ks * 512);
#pragma unroll
  for (int mt = 0; mt < 4; mt++)
#pragma unroll
    for (int ks = 0; ks < 2; ks++)
      vfA[mt][ks] = *(const f16x8v*)(vtb + mt * 65536 + ks * 512);
  rvA = rp[0];
  f32x4v acc[4][2] = {};
  int ig = ti * 2 + (col >> 3);
  int i_lo = col & 7;

#define FAV_BODY(IT, QF, VF, RV, QN, VN, RN, PREF, SEB)                        \
  {                                                                            \
    if (PREF) {                                                                \
      _Pragma("unroll") for (int ks = 0; ks < 4; ks++)                         \
        QN[ks] = *(const f16x8v*)(qtb + (size_t)((IT) + 1) * 8192 + ks * 512); \
      _Pragma("unroll") for (int mt = 0; mt < 4; mt++)                         \
        _Pragma("unroll") for (int ks = 0; ks < 2; ks++)                       \
          VN[mt][ks] = *(const f16x8v*)(vtb + mt * 65536 +                     \
                                        (size_t)(((IT) + 1) * 2 + ks) * 512);  \
      RN = rp[((IT) + 1) * 64];                                                \
    }                                                                          \
    f32x4v s0 = {}, s1 = {};                                                   \
    _Pragma("unroll") for (int ks = 0; ks < 4; ks++) {                         \
      s0 = mfma16(ka0[ks], QF[ks], s0);                                        \
      s1 = mfma16(ka1[ks], QF[ks], s1);                                        \
    }                                                                          \
    _Pragma("unroll") for (int rg = 0; rg < 4; rg++) {                         \
      int jl0 = tjb * 16 + quad * 4 + rg;                                      \
      sE[SEB][jl0 * 64 + ((ig ^ (jl0 & 7)) * 8) + i_lo] = (f16)(__expf(s0[rg]) * RV); \
      sE[SEB][(jl0 + 16) * 64 + ((ig ^ (jl0 & 7)) * 8) + i_lo] = (f16)(__expf(s1[rg]) * RV); \
    }                                                                          \
    asm volatile("s_waitcnt lgkmcnt(0)\n\ts_barrier" ::: "memory");            \
    _Pragma("unroll") for (int ks = 0; ks < 2; ks++) {                         \
      int sw = ((ks * 4 + quad) ^ (col & 7)) * 8;                              \
      f16x8v e0 = *(const f16x8v*)&sE[SEB][(jh * 32 + col) * 64 + sw];         \
      f16x8v e1 = *(const f16x8v*)&sE[SEB][(jh * 32 + 16 + col) * 64 + sw];    \
      acc[0][0] = mfma16(VF[0][ks], e0, acc[0][0]);                            \
      acc[0][1] = mfma16(VF[0][ks], e1, acc[0][1]);                            \
      acc[1][0] = mfma16(VF[1][ks], e0, acc[1][0]);                            \
      acc[1][1] = mfma16(VF[1][ks], e1, acc[1][1]);                            \
      acc[2][0] = mfma16(VF[2][ks], e0, acc[2][0]);                            \
      acc[2][1] = mfma16(VF[2][ks], e1, acc[2][1]);                            \
      acc[3][0] = mfma16(VF[3][ks], e0, acc[3][0]);                            \
      acc[3][1] = mfma16(VF[3][ks], e1, acc[3][1]);                            \
    }                                                                          \
  }

  for (int itp = 0; itp < 32; itp++) {
    int itA = itp * 2;
    FAV_BODY(itA, qfA, vfA, rvA, qfB, vfB, rvB, true, 0)
    FAV_BODY(itA + 1, qfB, vfB, rvB, qfA, vfA, rvA, itp < 31, 1)
  }
#undef FAV_BODY

  float gm = gamma[0];
  const float* xb = x + (size_t)b * 256 * 4096;
  float* ob = out + (size_t)b * 256 * 4096;
#pragma unroll
  for (int mt = 0; mt < 4; mt++)
#pragma unroll
    for (int jt = 0; jt < 2; jt++) {
      int c = cg * 64 + mt * 16 + quad * 4;
      int j = j0 + jh * 32 + jt * 16 + col;
#pragma unroll
      for (int rg = 0; rg < 4; rg++) {
        size_t off = (size_t)(c + rg) * 4096 + j;
        ob[off] = gm * acc[mt][jt][rg] + xb[off];
      }
    }
}

extern "C" void kernel_launch(void* const* d_in, const int* in_sizes, int n_in,
                              void* d_out, int out_size, void* d_ws, size_t ws_size,
                              hipStream_t stream) {
  (void)in_sizes; (void)n_in; (void)out_size; (void)ws_size;
  const float* x  = (const float*)d_in[0];
  const float* wq = (const float*)d_in[1];
  const float* bq = (const float*)d_in[2];
  const float* wk = (const float*)d_in[3];
  const float* bk = (const float*)d_in[4];
  const float* wv = (const float*)d_in[5];
  const float* bv = (const float*)d_in[6];
  const float* gm = (const float*)d_in[7];
  float* out = (float*)d_out;

  char* ws = (char*)d_ws;
  f16*  xh = (f16*)ws;                          // 8 MB fragment-tiled x
  f16*  qT = (f16*)(ws + 8388608);              // 4 MB fragment-tiled Q
  f16*  kT = (f16*)(ws + 12582912);             // 4 MB fragment-tiled K
  f16*  vT = (f16*)(ws + 16777216);             // 8 MB fragment-tiled V
  f16*  wh = (f16*)(ws + 25165824);             // 256 KB fragment-tiled W
  float* bcat    = (float*)(ws + 25427968);     // 2 KB
  float* rinv    = (float*)(ws + 25430016);     // 64 KB
  float* partial = (float*)(ws + 25495552);     // 4 MB: [b][64][4096]

  hipLaunchKernelGGL(k_wcvt, dim3(512), dim3(256), 0, stream, wq, bq, wk, bk, wv, bv, wh, bcat);
  hipLaunchKernelGGL(k_xsplit, dim3(64, 4, 4), dim3(256), 0, stream, x, xh);
  hipLaunchKernelGGL(k_proj, dim3(8, 8, 4), dim3(512), 0, stream, xh, wh, bcat, qT, kT, vT);
  hipLaunchKernelGGL(k_rows, dim3(32, 2, 4), dim3(512), 0, stream, qT, kT, partial);
  hipLaunchKernelGGL(k_rsum, dim3(16, 4), dim3(256), 0, stream, partial, rinv);
  hipLaunchKernelGGL(k_fav, dim3(256), dim3(512), 0, stream, qT, kT, vT, rinv, x, gm, out);
}

// Round 13
// 174.290 us; speedup vs baseline: 1.1391x; 1.1391x over previous
//
#include <hip/hip_runtime.h>
#include <hip/hip_bf16.h>

// ConvSelfAttentionModule: B=4, C=256, CQK=128, N=4096 (64x64), fp32 in/out.
// R21 = R20 resubmitted verbatim (R12 bench was an infra failure: container
// died twice; no counters). Theory unchanged:
// R20 = R8 (proven 178.4us best) + (1) wave-split 2-tile k_fav, (2) k_wcvt
// fused into k_xsplit.
// R11 lesson: V VMEM is the loaded pipe — AV re-tile (halve LDS reads,
// double V loads) regressed 63->83. The only remaining pure reduction in the
// R4 body: Q frags loaded 2x per wg (ti=w&3). Fix on R10's PASSING 2-pair-sE
// skeleton: wave w does QK for tile sel=w>>2 ONLY, all 64 j (ka[4][4]
// resident, k_rows pattern), i-subtile ti=w&3 -> Q loads 8->4 per wave per
// 2 tiles; MFMA/exp/sE-writes/V-loads per 2 tiles unchanged vs R4. Barrier/
// WAR structure byte-identical to R10 (passed).
//   k_xsplit : x -> fragment-tiled f16 + fused W convert [R16 + wcvt]
//   k_proj   : register-direct projections, no LDS/barriers [R16]
//   k_rows   : QK^T + exp + partial row sums (widened, 128 j/wg) [R15/R8]
//   k_rsum   : rinv[b][i] = 1 / sum_j exp(S[i,j]) [R15]
//   k_fav    : fused recompute+AV, wave-split 2-tile (above)

typedef _Float16 f16;
typedef _Float16 f16x4v __attribute__((ext_vector_type(4)));
typedef _Float16 f16x8v __attribute__((ext_vector_type(8)));
typedef float f32x4v __attribute__((ext_vector_type(4)));

static __device__ __forceinline__ f32x4v mfma16(f16x8v a, f16x8v b, f32x4v c) {
  // A-frag m=lane&15,k=quad*8+e; B-frag n=lane&15,k=quad*8+e
  // D: col(n)=lane&15, row(m)=quad*4+reg
  return __builtin_amdgcn_mfma_f32_16x16x32_f16(a, b, c, 0, 0, 0);
}

// ---------------- kernel 0: x transpose -> fragment-tiled f16, + W convert ----------------
// xTf elem (t,c): b*1048576 + (t>>4)*4096 + (c>>5)*512 + ((c>>3)&3)*128
//                 + (t&15)*8 + (c&7)
// wT  elem (o,c): (o>>4)*4096 + (c>>5)*512 + ((c>>3)&3)*128 + (o&15)*8 + (c&7)
__global__ void k_xsplit(const float* __restrict__ x, f16* __restrict__ xh,
                         const float* __restrict__ wq, const float* __restrict__ bq,
                         const float* __restrict__ wk, const float* __restrict__ bk,
                         const float* __restrict__ wv, const float* __restrict__ bv,
                         f16* __restrict__ wh, float* __restrict__ bcat) {
  // fused W convert: linear wg ids 0..511 each convert one W row (no deps)
  int id = blockIdx.x + 64 * (blockIdx.y + 4 * blockIdx.z);
  if (id < 512) {
    int o = id, c = threadIdx.x;
    const float* wrow; float bias;
    if (o < 128)      { wrow = wq + (size_t)o * 256;         bias = bq[o]; }
    else if (o < 256) { wrow = wk + (size_t)(o - 128) * 256; bias = bk[o - 128]; }
    else              { wrow = wv + (size_t)(o - 256) * 256; bias = bv[o - 256]; }
    wh[(size_t)(o >> 4) * 4096 + (size_t)(c >> 5) * 512 +
       (size_t)((c >> 3) & 3) * 128 + (o & 15) * 8 + (c & 7)] = (f16)wrow[c];
    if (c == 0) bcat[o] = bias;
  }
  __shared__ float t[64][65];
  int b = blockIdx.z, c0 = blockIdx.y * 64, n0 = blockIdx.x * 64;
  int tx = threadIdx.x & 63, ty = threadIdx.x >> 6;
  const float* xb = x + ((size_t)b * 256 + c0) * 4096 + n0;
#pragma unroll
  for (int r = ty; r < 64; r += 4) t[r][tx] = xb[(size_t)r * 4096 + tx];
  __syncthreads();
  f16* xbb = xh + (size_t)b * 1048576;
#pragma unroll
  for (int k2 = 0; k2 < 2; k2++) {
    int id2 = k2 * 256 + threadIdx.x;
    int tok = id2 & 63, oct = id2 >> 6;        // oct = 8-channel group 0..7
    int tt = n0 + tok;
    f16x8v v;
#pragma unroll
    for (int e = 0; e < 8; e++) v[e] = (f16)t[oct * 8 + e][tok];
    size_t addr = (size_t)(tt >> 4) * 4096 +
                  (size_t)((c0 >> 5) + (oct >> 2)) * 512 +
                  (size_t)(oct & 3) * 128 + (tt & 15) * 8;
    *(f16x8v*)&xbb[addr] = v;
  }
}

// ---------------- kernel 1: projections, register-direct [R16] ----------------
__global__ void __launch_bounds__(512, 1)
k_proj(const f16* __restrict__ xh, const f16* __restrict__ wh,
       const float* __restrict__ bcat, f16* __restrict__ qT,
       f16* __restrict__ kT, f16* __restrict__ vT) {
  int ob = blockIdx.x, th = blockIdx.y, b = blockIdx.z;
  int tid = threadIdx.x, l = tid & 63, w = tid >> 6;
  int col = l & 15, quad = l >> 4;
  int tt = w & 3, oh = w >> 2;
  int OT0 = ob * 4 + oh * 2;                   // first of 2 resident o-tiles
  const f16* wtb = wh + (size_t)OT0 * 4096 + l * 8;
  f16x8v wb[2][8];
#pragma unroll
  for (int jt = 0; jt < 2; jt++)
#pragma unroll
    for (int ks = 0; ks < 8; ks++)
      wb[jt][ks] = *(const f16x8v*)(wtb + jt * 4096 + ks * 512);
  float bias0 = bcat[OT0 * 16 + col];
  float bias1 = bcat[OT0 * 16 + 16 + col];
  const f16* atb = xh + (size_t)b * 1048576 + (size_t)(th * 32 + tt) * 4096 + l * 8;
  f16x8v afA[8], afB[8];
#pragma unroll
  for (int ks = 0; ks < 8; ks++) afA[ks] = *(const f16x8v*)(atb + ks * 512);

#define PROJ_BODY(IT, AF, AN, PREF)                                            \
  {                                                                            \
    if (PREF) {                                                                \
      _Pragma("unroll") for (int ks = 0; ks < 8; ks++)                         \
        AN[ks] = *(const f16x8v*)(atb + (size_t)((IT) + 1) * 16384 + ks * 512);\
    }                                                                          \
    f32x4v s0 = {}, s1 = {};                                                   \
    _Pragma("unroll") for (int ks = 0; ks < 8; ks++) {                         \
      s0 = mfma16(AF[ks], wb[0][ks], s0);                                      \
      s1 = mfma16(AF[ks], wb[1][ks], s1);                                      \
    }                                                                          \
    int T = th * 32 + (IT) * 4 + tt;                                           \
    if (ob < 4) {                                                              \
      f16* dst = (ob < 2) ? qT : kT;                                           \
      _Pragma("unroll") for (int jt = 0; jt < 2; jt++) {                       \
        int o = OT0 * 16 + jt * 16 + col;                                      \
        int d = o & 127;                                                       \
        float bs = jt ? bias1 : bias0;                                         \
        size_t base = (size_t)b * 524288 + (size_t)T * 2048 +                  \
                      (size_t)(d >> 5) * 512 + (size_t)((d >> 3) & 3) * 128 +  \
                      (d & 7);                                                 \
        float sv0 = jt ? s1[0] : s0[0], sv1 = jt ? s1[1] : s0[1];              \
        float sv2 = jt ? s1[2] : s0[2], sv3 = jt ? s1[3] : s0[3];              \
        dst[base + (quad * 4 + 0) * 8] = (f16)(sv0 + bs);                      \
        dst[base + (quad * 4 + 1) * 8] = (f16)(sv1 + bs);                      \
        dst[base + (quad * 4 + 2) * 8] = (f16)(sv2 + bs);                      \
        dst[base + (quad * 4 + 3) * 8] = (f16)(sv3 + bs);                      \
      }                                                                        \
    } else {                                                                   \
      int i0 = T * 16 + quad * 4;                                              \
      size_t ibase = (size_t)b * 1048576 + (size_t)(i0 >> 5) * 512 +           \
                     (size_t)((i0 >> 3) & 3) * 128 + (i0 & 7);                 \
      _Pragma("unroll") for (int jt = 0; jt < 2; jt++) {                       \
        int c = OT0 * 16 + jt * 16 + col - 256;                                \
        float bs = jt ? bias1 : bias0;                                         \
        f16x4v pv;                                                             \
        _Pragma("unroll") for (int rg = 0; rg < 4; rg++)                       \
          pv[rg] = (f16)((jt ? s1[rg] : s0[rg]) + bs);                         \
        *(f16x4v*)&vT[ibase + (size_t)(c >> 4) * 65536 + (c & 15) * 8] = pv;   \
      }                                                                        \
    }                                                                          \
  }

  for (int itp = 0; itp < 4; itp++) {
    int itA = itp * 2;
    PROJ_BODY(itA, afA, afB, true)
    PROJ_BODY(itA + 1, afB, afA, itp < 3)
  }
#undef PROJ_BODY
}

// ---------------- kernel 2: row sums of exp(S), widened (128 j per wg) [R8] ----------------
__global__ void __launch_bounds__(512, 2)
k_rows(const f16* __restrict__ qT, const f16* __restrict__ kT,
       float* __restrict__ partial) {
  int jblk = blockIdx.x, ih = blockIdx.y, b = blockIdx.z;
  int tid = threadIdx.x, l = tid & 63, w = tid >> 6;
  int col = l & 15;
  int ti = w & 3, jh = w >> 2;
  const f16* ktb = kT + (size_t)b * 524288 + (size_t)(jblk * 8 + jh * 4) * 2048 + l * 8;
  const f16* qtb = qT + (size_t)b * 524288 + (size_t)ti * 2048 + l * 8;
  f16x8v ka[4][4];
#pragma unroll
  for (int jt = 0; jt < 4; jt++)
#pragma unroll
    for (int ks = 0; ks < 4; ks++)
      ka[jt][ks] = *(const f16x8v*)(ktb + jt * 2048 + ks * 512);
  float* pout = partial + ((size_t)(b * 32 + jblk) * 2 + jh) * 4096 + ti * 16 + col;
  int it0 = ih * 32;
  f16x8v qfA[4], qfB[4];
#pragma unroll
  for (int ks = 0; ks < 4; ks++)
    qfA[ks] = *(const f16x8v*)(qtb + (size_t)it0 * 8192 + ks * 512);

#define ROWS_BODY(IT, QF, QN, PREF)                                           \
  {                                                                           \
    if (PREF) {                                                               \
      _Pragma("unroll") for (int ks = 0; ks < 4; ks++)                        \
        QN[ks] = *(const f16x8v*)(qtb + (size_t)((IT) + 1) * 8192 + ks * 512);\
    }                                                                         \
    f32x4v s[4] = {};                                                         \
    _Pragma("unroll") for (int ks = 0; ks < 4; ks++) {                        \
      s[0] = mfma16(ka[0][ks], QF[ks], s[0]);                                 \
      s[1] = mfma16(ka[1][ks], QF[ks], s[1]);                                 \
      s[2] = mfma16(ka[2][ks], QF[ks], s[2]);                                 \
      s[3] = mfma16(ka[3][ks], QF[ks], s[3]);                                 \
    }                                                                         \
    float t = 0.f;                                                            \
    _Pragma("unroll") for (int jt = 0; jt < 4; jt++)                          \
      _Pragma("unroll") for (int rg = 0; rg < 4; rg++)                        \
        t += __expf(s[jt][rg]);                                               \
    t += __shfl_xor(t, 16);                                                   \
    t += __shfl_xor(t, 32);                                                   \
    if (l < 16) pout[(size_t)(IT) * 64] = t;                                  \
  }

  for (int itp = 0; itp < 16; itp++) {
    int itA = it0 + itp * 2;
    ROWS_BODY(itA, qfA, qfB, true)
    ROWS_BODY(itA + 1, qfB, qfA, itp < 15)
  }
#undef ROWS_BODY
}

// ---------------- kernel 3: combine partials -> rinv = 1/rowsum ----------------
__global__ void k_rsum(const float* __restrict__ partial, float* __restrict__ rinv) {
  int b = blockIdx.y;
  int i = blockIdx.x * 256 + threadIdx.x;
  const float* p = partial + (size_t)b * 64 * 4096 + i;
  float s = 0.f;
#pragma unroll 8
  for (int jb = 0; jb < 64; jb++) s += p[(size_t)jb * 4096];
  rinv[(size_t)b * 4096 + i] = 1.0f / s;
}

// ---------------- kernel 4: fused recompute + AV, wave-split 2-tile ----------------
// Per wg: batch b, j-cols [j0,j0+64), all 256 c. Super-iter s (tiles 2s,
// 2s+1), pair p=s&1; wave (ti=w&3, sel=w>>2):
//   V loads for both tiles (used post-barrier)
//   QK for tile 2s+sel ONLY: all 64 j via resident ka[4][4], 16 MFMA
//   exp*rinv -> sE[p][sel] (same cell->writer bijection as R4, relabeled)
//   lgkmcnt(0); s_barrier   (one barrier per 2 tiles — R10-proven structure)
//   prefetch Q(2s+2+sel), rv  (overlaps AV)
//   AV both tiles (identical to R10/R4: acc[2][4], V c-tiles w*2,w*2+1)
// Q loads per wave per 2 tiles: 4 (was 8) — pure dedup, all else unchanged.
__global__ void __launch_bounds__(512, 1)
k_fav(const f16* __restrict__ qT, const f16* __restrict__ kT,
      const f16* __restrict__ vT, const float* __restrict__ rinv,
      const float* __restrict__ x, const float* __restrict__ gamma,
      float* __restrict__ out) {
  __shared__ f16 sE[2][2][4096];  // [pair][tile][64 j][64 i], XOR(j&7) groups
  // XCD-chunked swizzle: 256 wgs, 8 XCDs -> contiguous 32-wg slice per XCD.
  int wg = blockIdx.x;
  int lg = (wg & 7) * 32 + (wg >> 3);
  int b = lg >> 6, j0 = (lg & 63) * 64;
  int tid = threadIdx.x, l = tid & 63, w = tid >> 6;
  int col = l & 15, quad = l >> 4;
  int ti = w & 3, sel = w >> 2;
  const f16* ktb = kT + (size_t)b * 524288 + (size_t)(j0 / 16) * 2048 + l * 8;
  const f16* qtb = qT + (size_t)b * 524288 + (size_t)ti * 2048 + l * 8;
  const f16* vtb = vT + (size_t)b * 1048576 + (size_t)(w * 2) * 65536 + l * 8;
  const float* rp = rinv + (size_t)b * 4096 + ti * 16 + col;
  // K fragments: ALL 4 j-tiles resident (k_rows pattern, 64 VGPR)
  f16x8v ka[4][4];
#pragma unroll
  for (int jt = 0; jt < 4; jt++)
#pragma unroll
    for (int ks = 0; ks < 4; ks++)
      ka[jt][ks] = *(const f16x8v*)(ktb + jt * 2048 + ks * 512);
  f16x8v qf[4], vfA[2][2], vfB[2][2];
#pragma unroll
  for (int ks = 0; ks < 4; ks++)
    qf[ks] = *(const f16x8v*)(qtb + (size_t)sel * 8192 + ks * 512);
  float rv = rp[sel * 64];
  f32x4v acc[2][4] = {};
  int ig = ti * 2 + (col >> 3);
  int i_lo = col & 7;

#define FAV_WR(SJ, JT, P)                                                      \
  _Pragma("unroll") for (int rg = 0; rg < 4; rg++) {                           \
    int jl = (JT) * 16 + quad * 4 + rg;                                        \
    sE[P][sel][jl * 64 + ((ig ^ (jl & 7)) * 8) + i_lo] =                       \
        (f16)(__expf(SJ[rg]) * rv);                                            \
  }

#define FAV_AV(VF, P, SET)                                                     \
  {                                                                            \
    _Pragma("unroll") for (int ks = 0; ks < 2; ks++) {                         \
      int sw = ((ks * 4 + quad) ^ (col & 7)) * 8;                              \
      f16x8v e0 = *(const f16x8v*)&sE[P][SET][col * 64 + sw];                  \
      f16x8v e1 = *(const f16x8v*)&sE[P][SET][(16 + col) * 64 + sw];           \
      f16x8v e2 = *(const f16x8v*)&sE[P][SET][(32 + col) * 64 + sw];           \
      f16x8v e3 = *(const f16x8v*)&sE[P][SET][(48 + col) * 64 + sw];           \
      acc[0][0] = mfma16(VF[0][ks], e0, acc[0][0]);                            \
      acc[0][1] = mfma16(VF[0][ks], e1, acc[0][1]);                            \
      acc[0][2] = mfma16(VF[0][ks], e2, acc[0][2]);                            \
      acc[0][3] = mfma16(VF[0][ks], e3, acc[0][3]);                            \
      acc[1][0] = mfma16(VF[1][ks], e0, acc[1][0]);                            \
      acc[1][1] = mfma16(VF[1][ks], e1, acc[1][1]);                            \
      acc[1][2] = mfma16(VF[1][ks], e2, acc[1][2]);                            \
      acc[1][3] = mfma16(VF[1][ks], e3, acc[1][3]);                            \
    }                                                                          \
  }

  for (int s = 0; s < 32; s++) {
    int t0 = s * 2;
    int p = s & 1;
    // V fragments, tile t0 (issue early; used after barrier)
#pragma unroll
    for (int mt = 0; mt < 2; mt++)
#pragma unroll
      for (int ks = 0; ks < 2; ks++)
        vfA[mt][ks] = *(const f16x8v*)(vtb + mt * 65536 + (size_t)(t0 * 2 + ks) * 512);
    // QK for this wave's tile (t0+sel): all 64 j
    f32x4v sj0 = {}, sj1 = {}, sj2 = {}, sj3 = {};
#pragma unroll
    for (int ks = 0; ks < 4; ks++) {
      sj0 = mfma16(ka[0][ks], qf[ks], sj0);
      sj1 = mfma16(ka[1][ks], qf[ks], sj1);
      sj2 = mfma16(ka[2][ks], qf[ks], sj2);
      sj3 = mfma16(ka[3][ks], qf[ks], sj3);
    }
    // V fragments, tile t0+1
#pragma unroll
    for (int mt = 0; mt < 2; mt++)
#pragma unroll
      for (int ks = 0; ks < 2; ks++)
        vfB[mt][ks] = *(const f16x8v*)(vtb + mt * 65536 + (size_t)(t0 * 2 + 2 + ks) * 512);
    if (p) { FAV_WR(sj0, 0, 1) FAV_WR(sj1, 1, 1) FAV_WR(sj2, 2, 1) FAV_WR(sj3, 3, 1) }
    else   { FAV_WR(sj0, 0, 0) FAV_WR(sj1, 1, 0) FAV_WR(sj2, 2, 0) FAV_WR(sj3, 3, 0) }
    asm volatile("s_waitcnt lgkmcnt(0)\n\ts_barrier" ::: "memory");
    if (s < 31) {
#pragma unroll
      for (int ks = 0; ks < 4; ks++)
        qf[ks] = *(const f16x8v*)(qtb + (size_t)(t0 + 2 + sel) * 8192 + ks * 512);
      rv = rp[(size_t)(t0 + 2 + sel) * 64];
    }
    if (p) { FAV_AV(vfA, 1, 0) FAV_AV(vfB, 1, 1) }
    else   { FAV_AV(vfA, 0, 0) FAV_AV(vfB, 0, 1) }
  }
#undef FAV_WR
#undef FAV_AV

  float gm = gamma[0];
  const float* xb = x + (size_t)b * 256 * 4096;
  float* ob = out + (size_t)b * 256 * 4096;
#pragma unroll
  for (int mt = 0; mt < 2; mt++)
#pragma unroll
    for (int jt = 0; jt < 4; jt++) {
      int c = w * 32 + mt * 16 + quad * 4;
      int j = j0 + jt * 16 + col;
#pragma unroll
      for (int rg = 0; rg < 4; rg++) {
        size_t off = (size_t)(c + rg) * 4096 + j;
        ob[off] = gm * acc[mt][jt][rg] + xb[off];
      }
    }
}

extern "C" void kernel_launch(void* const* d_in, const int* in_sizes, int n_in,
                              void* d_out, int out_size, void* d_ws, size_t ws_size,
                              hipStream_t stream) {
  (void)in_sizes; (void)n_in; (void)out_size; (void)ws_size;
  const float* x  = (const float*)d_in[0];
  const float* wq = (const float*)d_in[1];
  const float* bq = (const float*)d_in[2];
  const float* wk = (const float*)d_in[3];
  const float* bk = (const float*)d_in[4];
  const float* wv = (const float*)d_in[5];
  const float* bv = (const float*)d_in[6];
  const float* gm = (const float*)d_in[7];
  float* out = (float*)d_out;

  char* ws = (char*)d_ws;
  f16*  xh = (f16*)ws;                          // 8 MB fragment-tiled x
  f16*  qT = (f16*)(ws + 8388608);              // 4 MB fragment-tiled Q
  f16*  kT = (f16*)(ws + 12582912);             // 4 MB fragment-tiled K
  f16*  vT = (f16*)(ws + 16777216);             // 8 MB fragment-tiled V
  f16*  wh = (f16*)(ws + 25165824);             // 256 KB fragment-tiled W
  float* bcat    = (float*)(ws + 25427968);     // 2 KB
  float* rinv    = (float*)(ws + 25430016);     // 64 KB
  float* partial = (float*)(ws + 25495552);     // 4 MB: [b][64][4096]

  hipLaunchKernelGGL(k_xsplit, dim3(64, 4, 4), dim3(256), 0, stream,
                     x, xh, wq, bq, wk, bk, wv, bv, wh, bcat);
  hipLaunchKernelGGL(k_proj, dim3(8, 8, 4), dim3(512), 0, stream, xh, wh, bcat, qT, kT, vT);
  hipLaunchKernelGGL(k_rows, dim3(32, 2, 4), dim3(512), 0, stream, qT, kT, partial);
  hipLaunchKernelGGL(k_rsum, dim3(16, 4), dim3(256), 0, stream, partial, rinv);
  hipLaunchKernelGGL(k_fav, dim3(256), dim3(512), 0, stream, qT, kT, vT, rinv, x, gm, out);
}